// Round 6
// baseline (279.365 us; speedup 1.0000x reference)
//
#include <hip/hip_runtime.h>
#include <math.h>

// Capsule dynamic routing — wave-autonomous fused kernel.
// B=256, C=10, N=1152, Din=8, U=16, 3 routing iterations.
// One block of 576 threads (9 waves) per (b,c). Wave w owns n in
// [128w, 128w+128); lane owns n0=128w+2*lane and n1=n0+1 with ALL 16 u:
// u_hat = 8 named float4 regs/lane. Routing logits b: 2 REGISTERS per lane
// (no LDS array, no RMW). exp and the b-update dot products are pure
// in-lane. Only the s/esum sum crosses lanes: in-wave fold-reduction
// (17 shuffles; final mapping lane l -> S[(l>>2)&15]), 17-float LDS stage
// per wave, ONE barrier per iteration (3 total; round-5 post-mortem showed
// the old structure's ~9 barriers + LDS round-trips were the serial floor).
// Named float4s only — per-thread arrays spilled in rounds 1-2.
// __launch_bounds__(576,1): no occupancy-floor VGPR cap (rounds 1-2:
// a cap below the live set causes GB-scale scratch thrash).

#define BATCH 256
#define CAPS  10
#define NIN   1152
#define DIN   8
#define UDIM  16
#define TPB   576

__global__ __launch_bounds__(TPB, 1) void capsule_routing_kernel(
    const float* __restrict__ x,   // (B, N, Din)
    const float* __restrict__ W,   // (C, N, Din, U)
    float* __restrict__ out)       // (B, C, U)
{
    const int blk  = blockIdx.x;     // c-major for L2 W-locality
    const int c    = blk >> 8;       // 0..9
    const int b    = blk & 255;      // 0..255
    const int t    = threadIdx.x;
    const int wave = t >> 6;         // 0..8
    const int lane = t & 63;
    const int n0   = (wave << 7) + (lane << 1);   // even n; n1 = n0+1

    // [buf][wave][0..15] = s partials, [16] = exp-sum partial
    __shared__ float ps[2][9][20];

    const float4* xq = (const float4*)(x + (size_t)b * (NIN * DIN) + n0 * DIN);
    const float4* wq = (const float4*)(W + (size_t)c * (NIN * DIN * UDIM)
                                         + (size_t)n0 * (DIN * UDIM));

    // ---- u_hat for (n0, n1): 8 named float4 accumulators ----
    float4 ua0, ua1, ua2, ua3, ub0, ub1, ub2, ub3;
    ua0.x=ua0.y=ua0.z=ua0.w=0.f; ua1.x=ua1.y=ua1.z=ua1.w=0.f;
    ua2.x=ua2.y=ua2.z=ua2.w=0.f; ua3.x=ua3.y=ua3.z=ua3.w=0.f;
    ub0.x=ub0.y=ub0.z=ub0.w=0.f; ub1.x=ub1.y=ub1.z=ub1.w=0.f;
    ub2.x=ub2.y=ub2.z=ub2.w=0.f; ub3.x=ub3.y=ub3.z=ub3.w=0.f;

// One din: 4 W-float4 loads + 16 FMAs, fenced to bound live registers.
#define UHG(A0,A1,A2,A3, XS, OFS) { \
    const float4 w0 = wq[(OFS)], w1 = wq[(OFS)+1], \
                 w2 = wq[(OFS)+2], w3 = wq[(OFS)+3]; \
    const float xs = (XS); \
    A0.x += xs*w0.x; A0.y += xs*w0.y; A0.z += xs*w0.z; A0.w += xs*w0.w; \
    A1.x += xs*w1.x; A1.y += xs*w1.y; A1.z += xs*w1.z; A1.w += xs*w1.w; \
    A2.x += xs*w2.x; A2.y += xs*w2.y; A2.z += xs*w2.z; A2.w += xs*w2.w; \
    A3.x += xs*w3.x; A3.y += xs*w3.y; A3.z += xs*w3.z; A3.w += xs*w3.w; } \
    __builtin_amdgcn_sched_barrier(0);

    {
        float4 xA = xq[0], xB = xq[1];          // x[b][n0][0..7]
        UHG(ua0,ua1,ua2,ua3, xA.x,  0) UHG(ua0,ua1,ua2,ua3, xA.y,  4)
        UHG(ua0,ua1,ua2,ua3, xA.z,  8) UHG(ua0,ua1,ua2,ua3, xA.w, 12)
        UHG(ua0,ua1,ua2,ua3, xB.x, 16) UHG(ua0,ua1,ua2,ua3, xB.y, 20)
        UHG(ua0,ua1,ua2,ua3, xB.z, 24) UHG(ua0,ua1,ua2,ua3, xB.w, 28)
        xA = xq[2]; xB = xq[3];                 // x[b][n1][0..7]
        UHG(ub0,ub1,ub2,ub3, xA.x, 32) UHG(ub0,ub1,ub2,ub3, xA.y, 36)
        UHG(ub0,ub1,ub2,ub3, xA.z, 40) UHG(ub0,ub1,ub2,ub3, xA.w, 44)
        UHG(ub0,ub1,ub2,ub3, xB.x, 48) UHG(ub0,ub1,ub2,ub3, xB.y, 52)
        UHG(ub0,ub1,ub2,ub3, xB.z, 56) UHG(ub0,ub1,ub2,ub3, xB.w, 60)
    }

    // routing logits in REGISTERS (softmax shift-invariance absorbs b=1)
    float bl0 = 0.f, bl1 = 0.f;

// Fold step: keep own half, receive partner's other half.
#define FOLD1(dst, lo, hi, bitmask) { \
    const float keep_ = (lane & (bitmask)) ? (hi) : (lo); \
    const float send_ = (lane & (bitmask)) ? (lo) : (hi); \
    dst = keep_ + __shfl_xor(send_, (bitmask)); }

    for (int it = 0; it < 3; ++it) {
        const int buf = it & 1;
        float4 p0, p1, p2, p3;
        float le = 0.f;
        if (it == 0) {   // uniform coupling: c = 1/N exactly
            p0.x=ua0.x+ub0.x; p0.y=ua0.y+ub0.y; p0.z=ua0.z+ub0.z; p0.w=ua0.w+ub0.w;
            p1.x=ua1.x+ub1.x; p1.y=ua1.y+ub1.y; p1.z=ua1.z+ub1.z; p1.w=ua1.w+ub1.w;
            p2.x=ua2.x+ub2.x; p2.y=ua2.y+ub2.y; p2.z=ua2.z+ub2.z; p2.w=ua2.w+ub2.w;
            p3.x=ua3.x+ub3.x; p3.y=ua3.y+ub3.y; p3.z=ua3.z+ub3.z; p3.w=ua3.w+ub3.w;
        } else {
            const float e0 = __expf(bl0), e1 = __expf(bl1);
            le = e0 + e1;
            p0.x=e0*ua0.x+e1*ub0.x; p0.y=e0*ua0.y+e1*ub0.y; p0.z=e0*ua0.z+e1*ub0.z; p0.w=e0*ua0.w+e1*ub0.w;
            p1.x=e0*ua1.x+e1*ub1.x; p1.y=e0*ua1.y+e1*ub1.y; p1.z=e0*ua1.z+e1*ub1.z; p1.w=e0*ua1.w+e1*ub1.w;
            p2.x=e0*ua2.x+e1*ub2.x; p2.y=e0*ua2.y+e1*ub2.y; p2.z=e0*ua2.z+e1*ub2.z; p2.w=e0*ua2.w+e1*ub2.w;
            p3.x=e0*ua3.x+e1*ub3.x; p3.y=e0*ua3.y+e1*ub3.y; p3.z=e0*ua3.z+e1*ub3.z; p3.w=e0*ua3.w+e1*ub3.w;
        }

        // ---- in-wave fold-reduction: 16 values over 64 lanes, 17 shuffles.
        // u-bit3<-lane-bit5, u-bit2<-b4, u-bit1<-b3, u-bit0<-b2:
        // final lane l holds S[(l>>2)&15].
        float g0,g1,g2,g3,g4,g5,g6,g7;
        FOLD1(g0, p0.x, p2.x, 32) FOLD1(g1, p0.y, p2.y, 32)
        FOLD1(g2, p0.z, p2.z, 32) FOLD1(g3, p0.w, p2.w, 32)
        FOLD1(g4, p1.x, p3.x, 32) FOLD1(g5, p1.y, p3.y, 32)
        FOLD1(g6, p1.z, p3.z, 32) FOLD1(g7, p1.w, p3.w, 32)
        float h0,h1,h2,h3;
        FOLD1(h0, g0, g4, 16) FOLD1(h1, g1, g5, 16)
        FOLD1(h2, g2, g6, 16) FOLD1(h3, g3, g7, 16)
        float k0,k1;
        FOLD1(k0, h0, h2, 8) FOLD1(k1, h1, h3, 8)
        float f;
        FOLD1(f, k0, k1, 4)
        f += __shfl_xor(f, 2);
        f += __shfl_xor(f, 1);
        // exp-sum: plain butterfly (lane 0 holds wave total)
        le += __shfl_xor(le, 1);  le += __shfl_xor(le, 2);
        le += __shfl_xor(le, 4);  le += __shfl_xor(le, 8);
        le += __shfl_xor(le, 16); le += __shfl_xor(le, 32);

        if ((lane & 3) == 0) ps[buf][wave][lane >> 2] = f;
        if (lane == 0)       ps[buf][wave][16] = le;
        __syncthreads();   // the ONLY barrier this iteration

        // ---- cross-wave reduce (lanes 0..16 of every wave), then in-wave
        // broadcast: every lane gets s[0..15] + esum. All register/DS ops.
        float acc = 0.f;
        if (lane < 17) {
            const float* psb = &ps[buf][0][0];
            #pragma unroll
            for (int w = 0; w < 9; ++w) acc += psb[w * 20 + lane];
        }
        float4 s0, s1, s2, s3;
        s0.x = __shfl(acc, 0);  s0.y = __shfl(acc, 1);
        s0.z = __shfl(acc, 2);  s0.w = __shfl(acc, 3);
        s1.x = __shfl(acc, 4);  s1.y = __shfl(acc, 5);
        s1.z = __shfl(acc, 6);  s1.w = __shfl(acc, 7);
        s2.x = __shfl(acc, 8);  s2.y = __shfl(acc, 9);
        s2.z = __shfl(acc, 10); s2.w = __shfl(acc, 11);
        s3.x = __shfl(acc, 12); s3.y = __shfl(acc, 13);
        s3.z = __shfl(acc, 14); s3.w = __shfl(acc, 15);
        const float esum = __shfl(acc, 16);

        const float inv = (it == 0) ? (1.0f / (float)NIN) : (1.0f / esum);
        s0.x*=inv; s0.y*=inv; s0.z*=inv; s0.w*=inv;
        s1.x*=inv; s1.y*=inv; s1.z*=inv; s1.w*=inv;
        s2.x*=inv; s2.y*=inv; s2.z*=inv; s2.w*=inv;
        s3.x*=inv; s3.y*=inv; s3.z*=inv; s3.w*=inv;

        // squash (redundant per-lane, register-only)
        const float sq =
            s0.x*s0.x + s0.y*s0.y + s0.z*s0.z + s0.w*s0.w +
            s1.x*s1.x + s1.y*s1.y + s1.z*s1.z + s1.w*s1.w +
            s2.x*s2.x + s2.y*s2.y + s2.z*s2.z + s2.w*s2.w +
            s3.x*s3.x + s3.y*s3.y + s3.z*s3.z + s3.w*s3.w;
        const float scale = sq / ((1.0f + sq) * sqrtf(sq + 1e-9f));
        s0.x*=scale; s0.y*=scale; s0.z*=scale; s0.w*=scale;
        s1.x*=scale; s1.y*=scale; s1.z*=scale; s1.w*=scale;
        s2.x*=scale; s2.y*=scale; s2.z*=scale; s2.w*=scale;
        s3.x*=scale; s3.y*=scale; s3.z*=scale; s3.w*=scale;

        if (it < 2) {
            // agreement: pure in-lane dot products
            bl0 += ua0.x*s0.x + ua0.y*s0.y + ua0.z*s0.z + ua0.w*s0.w
                 + ua1.x*s1.x + ua1.y*s1.y + ua1.z*s1.z + ua1.w*s1.w
                 + ua2.x*s2.x + ua2.y*s2.y + ua2.z*s2.z + ua2.w*s2.w
                 + ua3.x*s3.x + ua3.y*s3.y + ua3.z*s3.z + ua3.w*s3.w;
            bl1 += ub0.x*s0.x + ub0.y*s0.y + ub0.z*s0.z + ub0.w*s0.w
                 + ub1.x*s1.x + ub1.y*s1.y + ub1.z*s1.z + ub1.w*s1.w
                 + ub2.x*s2.x + ub2.y*s2.y + ub2.z*s2.z + ub2.w*s2.w
                 + ub3.x*s3.x + ub3.y*s3.y + ub3.z*s3.z + ub3.w*s3.w;
        } else if (wave == 0 && lane == 0) {
            float4* o = (float4*)(out + ((size_t)b * CAPS + c) * UDIM);
            o[0] = s0; o[1] = s1; o[2] = s2; o[3] = s3;
        }
    }
}

extern "C" void kernel_launch(void* const* d_in, const int* in_sizes, int n_in,
                              void* d_out, int out_size, void* d_ws, size_t ws_size,
                              hipStream_t stream) {
    const float* x = (const float*)d_in[0];   // (256, 1152, 8)
    const float* W = (const float*)d_in[1];   // (10, 1152, 8, 16)
    float* out = (float*)d_out;               // (256, 10, 16)
    capsule_routing_kernel<<<BATCH * CAPS, TPB, 0, stream>>>(x, W, out);
}

// Round 8
// 131.656 us; speedup vs baseline: 2.1219x; 2.1219x over previous
//
#include <hip/hip_runtime.h>
#include <math.h>

// Capsule dynamic routing — fused, quad-mapped, register-resident logits,
// software-pipelined W loads. B=256, C=10, N=1152, Din=8, U=16, 3 iters.
//
// ROUND-7 BUG FIX: x group stride. xq is float4*; n+=128 advances
// 128*Din = 1024 floats = 256 float4. Round 7 used xq[512*K] (2x stride),
// reading wrong/OOB x for k>=1 -> absmax 1.6e-4 (= output magnitude,
// i.e. totally wrong). Now xq[256*K], matching round 5's verified xp+=256.
//
// Mapping (round-5 coalescing-friendly): one block of 512 threads per
// (b,c). Thread t: u-quad base ub=(t&3)*4, gg=t>>2 in 0..127, owns
// n = gg + 128k for k=0..8. A quad's 4 lanes cover one 64-B W line ->
// each W dwordx4 wave-load touches 16 lines (round 6's lane-owns-n layout
// touched 64 lines/load and ran 3x slower).
//
// Routing logits b: NINE NAMED float registers per thread (replicated x4
// within each quad -> consistent by construction). No LDS b array, no RMW.
// One __syncthreads per routing iteration (3 total).
//
// u_hat phase: explicit A/B double-buffer prefetch (8 W float4 + 2 x float4
// per group) with NO sched_barrier fences -> ~16 loads in flight while
// FMA-ing (rounds 3-5 serialized group loads behind fences; that latency —
// not VALU, not bandwidth — was the 2x gap over the ~40us W-stream floor).
//
// Named float4/float regs only — per-thread arrays spilled (rounds 1-2).
// __launch_bounds__(512,1): no occupancy-floor VGPR cap (rounds 1-2: caps
// below the live set cause GB-scale scratch thrash; sentinel = WRITE_SIZE).

#define BATCH 256
#define CAPS  10
#define NIN   1152
#define DIN   8
#define UDIM  16
#define TPB   512

__global__ __launch_bounds__(TPB, 1) void capsule_routing_kernel(
    const float* __restrict__ x,   // (B, N, Din)
    const float* __restrict__ W,   // (C, N, Din, U)
    float* __restrict__ out)       // (B, C, U)
{
    const int blk  = blockIdx.x;     // c-major for L2 W-locality
    const int c    = blk >> 8;       // 0..9
    const int b    = blk & 255;      // 0..255
    const int t    = threadIdx.x;    // 0..511
    const int ub   = (t & 3) << 2;   // u base: 0,4,8,12
    const int gg   = t >> 2;         // 0..127
    const int wave = t >> 6;         // 0..7

    // [buf][wave][0..15]=s partials (u), [16]=exp-sum partial; pad to 20
    __shared__ float ps[2][8][20];

    const float4* xq = (const float4*)(x + (size_t)b * (NIN * DIN) + gg * DIN);
    const float4* wq = (const float4*)(W + (size_t)c * (NIN * DIN * UDIM)
                                         + gg * (DIN * UDIM) + ub);

    // ---- u_hat: 9 named float4 accumulators, A/B pipelined loads ----
    float4 uh0, uh1, uh2, uh3, uh4, uh5, uh6, uh7, uh8;
    float4 xa, xb_, w0, w1, w2, w3, w4, w5, w6, w7;     // buffer A
    float4 ya, yb_, v0, v1, v2, v3, v4, v5, v6, v7;     // buffer B

#define LOADA(K) { \
    xa  = xq[256*(K)];   xb_ = xq[256*(K)+1]; \
    w0 = wq[4096*(K)];    w1 = wq[4096*(K)+4]; \
    w2 = wq[4096*(K)+8];  w3 = wq[4096*(K)+12]; \
    w4 = wq[4096*(K)+16]; w5 = wq[4096*(K)+20]; \
    w6 = wq[4096*(K)+24]; w7 = wq[4096*(K)+28]; }
#define LOADB(K) { \
    ya  = xq[256*(K)];   yb_ = xq[256*(K)+1]; \
    v0 = wq[4096*(K)];    v1 = wq[4096*(K)+4]; \
    v2 = wq[4096*(K)+8];  v3 = wq[4096*(K)+12]; \
    v4 = wq[4096*(K)+16]; v5 = wq[4096*(K)+20]; \
    v6 = wq[4096*(K)+24]; v7 = wq[4096*(K)+28]; }
#define FMAA(D) { \
    D.x = xa.x*w0.x + xa.y*w1.x + xa.z*w2.x + xa.w*w3.x \
        + xb_.x*w4.x + xb_.y*w5.x + xb_.z*w6.x + xb_.w*w7.x; \
    D.y = xa.x*w0.y + xa.y*w1.y + xa.z*w2.y + xa.w*w3.y \
        + xb_.x*w4.y + xb_.y*w5.y + xb_.z*w6.y + xb_.w*w7.y; \
    D.z = xa.x*w0.z + xa.y*w1.z + xa.z*w2.z + xa.w*w3.z \
        + xb_.x*w4.z + xb_.y*w5.z + xb_.z*w6.z + xb_.w*w7.z; \
    D.w = xa.x*w0.w + xa.y*w1.w + xa.z*w2.w + xa.w*w3.w \
        + xb_.x*w4.w + xb_.y*w5.w + xb_.z*w6.w + xb_.w*w7.w; }
#define FMAB(D) { \
    D.x = ya.x*v0.x + ya.y*v1.x + ya.z*v2.x + ya.w*v3.x \
        + yb_.x*v4.x + yb_.y*v5.x + yb_.z*v6.x + yb_.w*v7.x; \
    D.y = ya.x*v0.y + ya.y*v1.y + ya.z*v2.y + ya.w*v3.y \
        + yb_.x*v4.y + yb_.y*v5.y + yb_.z*v6.y + yb_.w*v7.y; \
    D.z = ya.x*v0.z + ya.y*v1.z + ya.z*v2.z + ya.w*v3.z \
        + yb_.x*v4.z + yb_.y*v5.z + yb_.z*v6.z + yb_.w*v7.z; \
    D.w = ya.x*v0.w + ya.y*v1.w + ya.z*v2.w + ya.w*v3.w \
        + yb_.x*v4.w + yb_.y*v5.w + yb_.z*v6.w + yb_.w*v7.w; }

    LOADA(0) LOADB(1)
    FMAA(uh0) LOADA(2)
    FMAB(uh1) LOADB(3)
    FMAA(uh2) LOADA(4)
    FMAB(uh3) LOADB(5)
    FMAA(uh4) LOADA(6)
    FMAB(uh5) LOADB(7)
    FMAA(uh6) LOADA(8)
    FMAB(uh7)
    FMAA(uh8)

    // routing logits in registers (softmax shift-invariance absorbs b=1)
    float bl0=0.f, bl1=0.f, bl2=0.f, bl3=0.f, bl4=0.f,
          bl5=0.f, bl6=0.f, bl7=0.f, bl8=0.f;

    for (int it = 0; it < 3; ++it) {
        const int buf = it & 1;
        float4 p;
        float le = 0.f;
        if (it == 0) {   // uniform coupling: c = 1/N exactly, no exp
            p.x = uh0.x+uh1.x+uh2.x+uh3.x+uh4.x+uh5.x+uh6.x+uh7.x+uh8.x;
            p.y = uh0.y+uh1.y+uh2.y+uh3.y+uh4.y+uh5.y+uh6.y+uh7.y+uh8.y;
            p.z = uh0.z+uh1.z+uh2.z+uh3.z+uh4.z+uh5.z+uh6.z+uh7.z+uh8.z;
            p.w = uh0.w+uh1.w+uh2.w+uh3.w+uh4.w+uh5.w+uh6.w+uh7.w+uh8.w;
        } else {
            p.x = p.y = p.z = p.w = 0.f;
#define ACCP(BL, UH) { \
            const float e = __expf(BL); le += e; \
            p.x += e*UH.x; p.y += e*UH.y; p.z += e*UH.z; p.w += e*UH.w; }
            ACCP(bl0, uh0) ACCP(bl1, uh1) ACCP(bl2, uh2)
            ACCP(bl3, uh3) ACCP(bl4, uh4) ACCP(bl5, uh5)
            ACCP(bl6, uh6) ACCP(bl7, uh7) ACCP(bl8, uh8)
        }

        // reduce over the wave's 16 gg-groups (lane bits 2..5)
        #pragma unroll
        for (int mk = 4; mk <= 32; mk <<= 1) {
            p.x += __shfl_xor(p.x, mk); p.y += __shfl_xor(p.y, mk);
            p.z += __shfl_xor(p.z, mk); p.w += __shfl_xor(p.w, mk);
        }
        if (it != 0) {
            #pragma unroll
            for (int mk = 4; mk <= 32; mk <<= 1) le += __shfl_xor(le, mk);
        }
        if ((t & 63) < 4) *(float4*)(&ps[buf][wave][ub]) = p;
        if ((t & 63) == 0) ps[buf][wave][16] = le;
        __syncthreads();    // the ONLY barrier this iteration

        // every thread: gather its u-quad of s + esum from the 8 waves
        float4 s; s.x = s.y = s.z = s.w = 0.f;
        float esum = 0.f;
        #pragma unroll
        for (int w = 0; w < 8; ++w) {
            const float4 q = *(const float4*)(&ps[buf][w][ub]);
            s.x += q.x; s.y += q.y; s.z += q.z; s.w += q.w;
            esum += ps[buf][w][16];
        }
        const float inv = (it == 0) ? (1.0f / (float)NIN) : (1.0f / esum);
        s.x *= inv; s.y *= inv; s.z *= inv; s.w *= inv;

        // squash: |s|^2 over all 16 u via 2 quad shuffles
        float sq = s.x*s.x + s.y*s.y + s.z*s.z + s.w*s.w;
        sq += __shfl_xor(sq, 1);
        sq += __shfl_xor(sq, 2);
        const float scale = sq / ((1.0f + sq) * sqrtf(sq + 1e-9f));
        s.x *= scale; s.y *= scale; s.z *= scale; s.w *= scale;

        if (it < 2) {
            // agreement: quad-partial dot + 2 shuffles -> full 16-u dot
#define BUPD(BL, UH) { \
            float q = UH.x*s.x + UH.y*s.y + UH.z*s.z + UH.w*s.w; \
            q += __shfl_xor(q, 1); q += __shfl_xor(q, 2); \
            BL += q; }
            BUPD(bl0, uh0) BUPD(bl1, uh1) BUPD(bl2, uh2)
            BUPD(bl3, uh3) BUPD(bl4, uh4) BUPD(bl5, uh5)
            BUPD(bl6, uh6) BUPD(bl7, uh7) BUPD(bl8, uh8)
        } else if (t < 4) {
            // threads 0..3 hold v[ub..ub+3] -> one float4 store each
            ((float4*)(out + ((size_t)b * CAPS + c) * UDIM))[t & 3] = s;
        }
    }
}

extern "C" void kernel_launch(void* const* d_in, const int* in_sizes, int n_in,
                              void* d_out, int out_size, void* d_ws, size_t ws_size,
                              hipStream_t stream) {
    const float* x = (const float*)d_in[0];   // (256, 1152, 8)
    const float* W = (const float*)d_in[1];   // (10, 1152, 8, 16)
    float* out = (float*)d_out;               // (256, 10, 16)
    capsule_routing_kernel<<<BATCH * CAPS, TPB, 0, stream>>>(x, W, out);
}